// Round 6
// baseline (124.445 us; speedup 1.0000x reference)
//
#include <hip/hip_runtime.h>

typedef __attribute__((ext_vector_type(4))) float f32x4;
typedef __bf16 bf16x8 __attribute__((ext_vector_type(8)));
typedef unsigned short ushort_t;

#define T_TOK 8192   // B*S
#define DIM   1024   // D
#define NRCOL 2048   // N_FEAT * R

#define VMW(n)  asm volatile("s_waitcnt vmcnt(" #n ")" ::: "memory")
#define SB0()   __builtin_amdgcn_sched_barrier(0)
#define BAR()   __builtin_amdgcn_s_barrier()

template<int V> struct IC { static constexpr int value = V; };

static __device__ __forceinline__ unsigned short f2bf(float f) {
  unsigned int u = __builtin_bit_cast(unsigned int, f);
  u += 0x7fffu + ((u >> 16) & 1u);          // RNE
  return (unsigned short)(u >> 16);
}
static __device__ __forceinline__ float bfbits2f(unsigned int lo16) {
  return __builtin_bit_cast(float, lo16 << 16);
}
static __device__ __forceinline__ void gload16(const void* g, void* l) {
  __builtin_amdgcn_global_load_lds((const __attribute__((address_space(1))) void*)g,
                                   (__attribute__((address_space(3))) void*)l, 16, 0, 0);
}

// ---------------- f32 -> bf16 straight cast (x) ----------------
__global__ __launch_bounds__(256) void cvt_f32_bf16(const float* __restrict__ in,
                                                    unsigned short* __restrict__ out,
                                                    int n4) {
  int i = blockIdx.x * 256 + threadIdx.x;
  const int stride = gridDim.x * 256;
  const float4* in4 = (const float4*)in;
  uint2* o4 = (uint2*)out;
  for (; i < n4; i += stride) {
    float4 v = in4[i];
    uint2 o;
    o.x = (unsigned)f2bf(v.x) | ((unsigned)f2bf(v.y) << 16);
    o.y = (unsigned)f2bf(v.z) | ((unsigned)f2bf(v.w) << 16);
    o4[i] = o;
  }
}

// ---------------- tiled transpose + cast ----------------
__global__ __launch_bounds__(256) void tcvt(const float* __restrict__ src,
                                            unsigned short* __restrict__ dst,
                                            int rows, int cols,
                                            long sstride, long dstride) {
  src += (size_t)blockIdx.z * sstride;
  dst += (size_t)blockIdx.z * dstride;
  __shared__ float tile[32][33];
  const int tx = threadIdx.x & 31, ty = threadIdx.x >> 5;
  const int r0 = blockIdx.y * 32, c0 = blockIdx.x * 32;
  #pragma unroll
  for (int i = 0; i < 32; i += 8)
    tile[ty + i][tx] = src[(size_t)(r0 + ty + i) * cols + c0 + tx];
  __syncthreads();
  #pragma unroll
  for (int i = 0; i < 32; i += 8)
    dst[(size_t)(c0 + ty + i) * rows + r0 + tx] = f2bf(tile[tx][ty + i]);
}

// =====================================================================
// gemmT: C[M,N] = A[M,K]*Bt[N,K]^T. 256x128 tile, BK=64, 512 thr = 8
// waves (4M x 2N, wave owns 64x64). Triple-buffered LDS, one barrier +
// one counted vmcnt(6) per K-tile (R5 ledger, verified). New this round:
// K-loop unrolled x3 so LDS slot indices are COMPILE-TIME; all ds_read
// offsets precomputed; staging uses 6 persistent per-thread pointers
// advanced by 64 elems/tile -> per-tile VALU ~350 -> ~30 ops.
// =====================================================================
template<int K, bool OUT_BF16>
__global__ __launch_bounds__(512, 2) void gemmT(const ushort_t* __restrict__ A,
                                                const ushort_t* __restrict__ Bt,
                                                void* __restrict__ Cp, int N) {
  constexpr int nt = K >> 6;
  constexpr int NT3 = (nt + 2) / 3;
  __shared__ ushort_t As[3][256 * 64];
  __shared__ ushort_t Bs[3][128 * 64];
  const int tid = threadIdx.x;
  const int nx = gridDim.x;
  const int orig = blockIdx.y * nx + blockIdx.x;
  const int q = (nx * gridDim.y) >> 3;          // grids are multiples of 8
  const int swz = (orig & 7) * q + (orig >> 3);
  const int bx = swz % nx, by = swz / nx;

  const int lane = tid & 63, wv = tid >> 6;
  const int wm = wv >> 1, wn = wv & 1;          // 4M x 2N
  const int lrow = lane & 15, lk = lane >> 4;

  const ushort_t* Ab = A + (size_t)by * 256 * K;
  const ushort_t* Bb = Bt + (size_t)bx * 128 * K;

  // persistent staging pointers (kt advances by +64 elems per tile)
  const int rs = tid >> 3;                      // staging row within 64-row round
  const int cs = (tid & 7) ^ (rs & 7);          // swizzled 16B chunk
  const ushort_t* pA[4];
  const ushort_t* pB[2];
  #pragma unroll
  for (int r = 0; r < 4; ++r) pA[r] = Ab + (size_t)(r * 64 + rs) * K + cs * 8;
  #pragma unroll
  for (int r = 0; r < 2; ++r) pB[r] = Bb + (size_t)(r * 64 + rs) * K + cs * 8;
  const int dA = tid * 8;                       // LDS dest elems (+ r*4096)

  // precomputed swizzled ds_read offsets (elems)
  int offA[4][2], offB[4][2];
  #pragma unroll
  for (int m = 0; m < 4; ++m) {
    const int ra = wm * 64 + m * 16 + lrow;
    const int rb = wn * 64 + m * 16 + lrow;
    #pragma unroll
    for (int ks = 0; ks < 2; ++ks) {
      offA[m][ks] = ra * 64 + ((ks * 4 + lk) ^ (ra & 7)) * 8;
      offB[m][ks] = rb * 64 + ((ks * 4 + lk) ^ (rb & 7)) * 8;
    }
  }

  f32x4 acc[4][4];
  #pragma unroll
  for (int m = 0; m < 4; ++m)
    #pragma unroll
    for (int n = 0; n < 4; ++n)
      acc[m][n] = (f32x4){0.f, 0.f, 0.f, 0.f};

  // prologue: tile0 -> slot0, tile1 -> slot1; tile1's 6 stay in flight
  #pragma unroll
  for (int r = 0; r < 4; ++r) gload16(pA[r], (void*)&As[0][r * 4096 + dA]);
  #pragma unroll
  for (int r = 0; r < 2; ++r) gload16(pB[r], (void*)&Bs[0][r * 4096 + dA]);
  #pragma unroll
  for (int r = 0; r < 4; ++r) gload16(pA[r] + 64, (void*)&As[1][r * 4096 + dA]);
  #pragma unroll
  for (int r = 0; r < 2; ++r) gload16(pB[r] + 64, (void*)&Bs[1][r * 4096 + dA]);
  #pragma unroll
  for (int r = 0; r < 4; ++r) pA[r] += 128;
  pB[0] += 128; pB[1] += 128;
  VMW(6); SB0(); BAR(); SB0();

  int t = 0;
  auto body = [&](auto SC) {
    constexpr int S = SC.value;
    constexpr int S2 = (S + 2) % 3;
    if (t >= nt) return;
    bf16x8 av[4][2], bv[4][2];
    #pragma unroll
    for (int m = 0; m < 4; ++m)
      #pragma unroll
      for (int ks = 0; ks < 2; ++ks) {
        av[m][ks] = *(const bf16x8*)&As[S][offA[m][ks]];
        bv[m][ks] = *(const bf16x8*)&Bs[S][offB[m][ks]];
      }
    if (t + 2 < nt) {
      #pragma unroll
      for (int r = 0; r < 4; ++r) gload16(pA[r], (void*)&As[S2][r * 4096 + dA]);
      #pragma unroll
      for (int r = 0; r < 2; ++r) gload16(pB[r], (void*)&Bs[S2][r * 4096 + dA]);
    }
    __builtin_amdgcn_s_setprio(1);
    #pragma unroll
    for (int ks = 0; ks < 2; ++ks)
      #pragma unroll
      for (int m = 0; m < 4; ++m)
        #pragma unroll
        for (int n = 0; n < 4; ++n)
          acc[m][n] = __builtin_amdgcn_mfma_f32_16x16x32_bf16(av[m][ks], bv[n][ks], acc[m][n], 0, 0, 0);
    __builtin_amdgcn_s_setprio(0);
    SB0();
    if (t + 2 < nt) { VMW(6); } else { VMW(0); }
    SB0(); BAR(); SB0();
    #pragma unroll
    for (int r = 0; r < 4; ++r) pA[r] += 64;
    pB[0] += 64; pB[1] += 64;
    ++t;
  };
  #pragma unroll 1
  for (int i = 0; i < NT3; ++i) {
    body(IC<0>{}); body(IC<1>{}); body(IC<2>{});
  }

  // epilogue: C/D layout col=lane&15, row=(lane>>4)*4+j
  #pragma unroll
  for (int m = 0; m < 4; ++m) {
    const int row0 = by * 256 + wm * 64 + m * 16 + lk * 4;
    #pragma unroll
    for (int n = 0; n < 4; ++n) {
      const int col = bx * 128 + wn * 64 + n * 16 + lrow;
      #pragma unroll
      for (int j = 0; j < 4; ++j) {
        const size_t idx = (size_t)(row0 + j) * N + col;
        if constexpr (OUT_BF16) ((ushort_t*)Cp)[idx] = f2bf(acc[m][n][j]);
        else                    ((float*)Cp)[idx] = acc[m][n][j];
      }
    }
  }
}

// ---------------- middle: h_all, router softmax, M = sum_p w (x) h ----------------
__global__ __launch_bounds__(256) void middle_kernel(const unsigned short* __restrict__ AH,
                                                     const float* __restrict__ fp,
                                                     const float* __restrict__ femb,
                                                     const float* __restrict__ Wr,
                                                     unsigned short* __restrict__ Mout,
                                                     float* __restrict__ auxout) {
  __shared__ float G[16][16];
  __shared__ float hs[4][2][128];
  __shared__ float wsm[4][2][16];
  const int tid = threadIdx.x;
  {
    const int n = tid >> 4, j = tid & 15;
    float s = 0.f;
    #pragma unroll
    for (int ds = 0; ds < 64; ++ds) s += femb[n * 64 + ds] * Wr[ds * 16 + j];
    G[n][j] = s;
  }
  const int wv = tid >> 6, l = tid & 63;
  const int t = blockIdx.x * 4 + wv;

  float p0[16], p1[16];
  #pragma unroll
  for (int n = 0; n < 16; ++n) {
    p0[n] = fp[t * 16 + n];
    p1[n] = fp[T_TOK * 16 + t * 16 + n];
  }

  float h00 = 0.f, h01 = 0.f, h10 = 0.f, h11 = 0.f;
  const unsigned short* ahrow = AH + (size_t)t * NRCOL;
  #pragma unroll
  for (int n = 0; n < 16; ++n) {
    const unsigned int v = *(const unsigned int*)(ahrow + n * 128 + 2 * l);
    const float a0 = bfbits2f(v & 0xffffu);
    const float a1 = bfbits2f(v >> 16);
    h00 += a0 * p0[n]; h01 += a1 * p0[n];
    h10 += a0 * p1[n]; h11 += a1 * p1[n];
  }
  hs[wv][0][2 * l] = h00; hs[wv][0][2 * l + 1] = h01;
  hs[wv][1][2 * l] = h10; hs[wv][1][2 * l + 1] = h11;
  __syncthreads();

  if (l < 32) {
    const int p = l >> 4, j = l & 15;
    float s = 0.f;
    #pragma unroll
    for (int n = 0; n < 16; ++n) s += (p ? p1[n] : p0[n]) * G[n][j];
    // 4 independent chains — breaks the 128-long serial FMA dependency
    const float* hp = hs[wv][p];
    const float* wr = Wr + 64 * 16 + j;
    float s0 = 0.f, s1 = 0.f, s2 = 0.f, s3 = 0.f;
    #pragma unroll
    for (int r = 0; r < 128; r += 4) {
      s0 += hp[r]     * wr[(r)     * 16];
      s1 += hp[r + 1] * wr[(r + 1) * 16];
      s2 += hp[r + 2] * wr[(r + 2) * 16];
      s3 += hp[r + 3] * wr[(r + 3) * 16];
    }
    s += (s0 + s1) + (s2 + s3);
    float mx = s;
    #pragma unroll
    for (int d = 1; d < 16; d <<= 1) mx = fmaxf(mx, __shfl_xor(mx, d, 64));
    const float e = __expf(s - mx);
    float sum = e;
    #pragma unroll
    for (int d = 1; d < 16; d <<= 1) sum += __shfl_xor(sum, d, 64);
    wsm[wv][p][j] = e / sum;
  }
  __syncthreads();

  unsigned short* mrow = Mout + (size_t)t * NRCOL;
  #pragma unroll
  for (int n = 0; n < 16; ++n) {
    const float w0 = wsm[wv][0][n], w1 = wsm[wv][1][n];
    const float m0 = w0 * h00 + w1 * h10;
    const float m1 = w0 * h01 + w1 * h11;
    const unsigned int pk = (unsigned)f2bf(m0) | ((unsigned)f2bf(m1) << 16);
    *(unsigned int*)(mrow + n * 128 + 2 * l) = pk;
  }
  if (blockIdx.x == 0 && tid == 0) auxout[0] = 0.f;
}

extern "C" void kernel_launch(void* const* d_in, const int* in_sizes, int n_in,
                              void* d_out, int out_size, void* d_ws, size_t ws_size,
                              hipStream_t stream) {
  const float* x    = (const float*)d_in[0];
  const float* fp   = (const float*)d_in[1];
  const float* fk   = (const float*)d_in[2];
  const float* rk   = (const float*)d_in[3];
  const float* femb = (const float*)d_in[4];
  const float* Wr   = (const float*)d_in[5];
  float* out = (float*)d_out;

  char* ws = (char*)d_ws;
  unsigned short* Xbf = (unsigned short*)ws;
  unsigned short* W1t = (unsigned short*)(ws + 16u * 1024 * 1024);
  unsigned short* Mb  = (unsigned short*)ws;
  unsigned short* W2t = (unsigned short*)(ws + 32u * 1024 * 1024);
  unsigned short* AH  = (unsigned short*)(ws + 36u * 1024 * 1024);

  cvt_f32_bf16<<<2048, 256, 0, stream>>>(x, Xbf, (T_TOK * DIM) / 4);
  tcvt<<<dim3(128 / 32, 1024 / 32, 16), 256, 0, stream>>>(fk, W1t, 1024, 128,
                                                          1024L * 128, 128L * 1024);
  tcvt<<<dim3(1024 / 32, 2048 / 32, 1), 256, 0, stream>>>(rk, W2t, 2048, 1024, 0, 0);
  // all_h = Xbf @ W1t^T -> AH bf16 [8192][2048]
  gemmT<1024, true><<<dim3(NRCOL / 128, T_TOK / 256), 512, 0, stream>>>(Xbf, W1t, AH, NRCOL);
  middle_kernel<<<T_TOK / 4, 256, 0, stream>>>(AH, fp, femb, Wr, Mb, out + 8388608);
  // output = Mb @ W2t^T -> f32 d_out [8192][1024]
  gemmT<2048, false><<<dim3(DIM / 128, T_TOK / 256), 512, 0, stream>>>(Mb, W2t, out, DIM);
}

// Round 8
// 115.903 us; speedup vs baseline: 1.0737x; 1.0737x over previous
//
#include <hip/hip_runtime.h>

typedef __attribute__((ext_vector_type(4))) float f32x4;
typedef __bf16 bf16x8 __attribute__((ext_vector_type(8)));
typedef unsigned short ushort_t;

#define T_TOK 8192   // B*S
#define DIM   1024   // D
#define NRCOL 2048   // N_FEAT * R

#define VMW(n)  asm volatile("s_waitcnt vmcnt(" #n ")" ::: "memory")
#define SB0()   __builtin_amdgcn_sched_barrier(0)
#define BAR()   __builtin_amdgcn_s_barrier()

static __device__ __forceinline__ unsigned short f2bf(float f) {
  unsigned int u = __builtin_bit_cast(unsigned int, f);
  u += 0x7fffu + ((u >> 16) & 1u);          // RNE
  return (unsigned short)(u >> 16);
}
static __device__ __forceinline__ float bfbits2f(unsigned int lo16) {
  return __builtin_bit_cast(float, lo16 << 16);
}
static __device__ __forceinline__ void gload16(const void* g, void* l) {
  __builtin_amdgcn_global_load_lds((const __attribute__((address_space(1))) void*)g,
                                   (__attribute__((address_space(3))) void*)l, 16, 0, 0);
}

// ---------------- f32 -> bf16 straight cast (x) ----------------
__global__ __launch_bounds__(256) void cvt_f32_bf16(const float* __restrict__ in,
                                                    unsigned short* __restrict__ out,
                                                    int n4) {
  int i = blockIdx.x * 256 + threadIdx.x;
  const int stride = gridDim.x * 256;
  const float4* in4 = (const float4*)in;
  uint2* o4 = (uint2*)out;
  for (; i < n4; i += stride) {
    float4 v = in4[i];
    uint2 o;
    o.x = (unsigned)f2bf(v.x) | ((unsigned)f2bf(v.y) << 16);
    o.y = (unsigned)f2bf(v.z) | ((unsigned)f2bf(v.w) << 16);
    o4[i] = o;
  }
}

// ---------------- tiled transpose + cast ----------------
__global__ __launch_bounds__(256) void tcvt(const float* __restrict__ src,
                                            unsigned short* __restrict__ dst,
                                            int rows, int cols,
                                            long sstride, long dstride) {
  src += (size_t)blockIdx.z * sstride;
  dst += (size_t)blockIdx.z * dstride;
  __shared__ float tile[32][33];
  const int tx = threadIdx.x & 31, ty = threadIdx.x >> 5;
  const int r0 = blockIdx.y * 32, c0 = blockIdx.x * 32;
  #pragma unroll
  for (int i = 0; i < 32; i += 8)
    tile[ty + i][tx] = src[(size_t)(r0 + ty + i) * cols + c0 + tx];
  __syncthreads();
  #pragma unroll
  for (int i = 0; i < 32; i += 8)
    dst[(size_t)(c0 + ty + i) * rows + r0 + tx] = f2bf(tile[tx][ty + i]);
}

// =====================================================================
// gemmP: C[M,N] = A[M,K]*Bt[N,K]^T. BM x 256 tile, 512 thr = 8 waves
// (2M x 4N, wave = BM/2 x 64). 3-slot LDS. 2 phases/tile with STRICT
// >=1-phase read-ahead (no MFMA ever waits on a just-issued ds_read):
//   P1: stage(t+2); read own bv23 (used P2); MFMA H0(n0-1)
//       VMW(LPT counted) + BAR   -> slot t+1 now valid
//   P2: read t+1's av + bv01 from slot s1 (used t+1 P1); MFMA H1(n2-3)
//       BAR
// av double-buffered by tile parity (compile-time via full unroll);
// bv01/bv23 single-buffered (reload strictly after last use).
// vmcnt ledger: outstanding at P1-end = LPT(t+1) + LPT(t+2) = 2*LPT;
// VMW(LPT) retires t+1's stage, leaves t+2's in flight.
// k-step frag offset: chunk = (ks*4+lk) ^ (row & (CH-1)); as elem
// offset this is base ^ (ks*32)   [R6 bug: had ^(ks*16) — wrong slice]
// =====================================================================
template<int BM, int BK, int K, bool OUT_BF16>
__global__ __launch_bounds__(512, 2) void gemmP(const ushort_t* __restrict__ A,
                                                const ushort_t* __restrict__ Bt,
                                                void* __restrict__ Cp, int N) {
  constexpr int nt = K / BK;
  constexpr int KS = BK / 32;              // 16x16x32 k-steps per tile
  constexpr int MF = BM / 32;              // m-frags per wave
  constexpr int CH = BK / 8;               // 16B chunks per LDS row
  constexpr int AR = BM * BK * 2 / 8192;   // A staging rounds
  constexpr int BR = 256 * BK * 2 / 8192;  // B staging rounds
  constexpr int LPT = AR + BR;
  __shared__ ushort_t As[3][BM * BK];
  __shared__ ushort_t Bs[3][256 * BK];

  const int tid = threadIdx.x;
  const int nx = gridDim.x;
  const int orig = blockIdx.y * nx + blockIdx.x;
  const int q = (nx * gridDim.y) >> 3;     // grids are multiples of 8
  const int swz = (orig & 7) * q + (orig >> 3);
  const int bx = swz % nx, by = swz / nx;

  const int lane = tid & 63, wv = tid >> 6;
  const int wm = wv >> 2, wn = wv & 3;     // 2M x 4N
  const int lrow = lane & 15, lk = lane >> 4;

  const ushort_t* Ab = A + (size_t)by * BM * K;
  const ushort_t* Bb = Bt + (size_t)bx * 256 * K;

  // persistent staging pointers (+BK elems per tile)
  const int srow = tid * 16 / (BK * 2);            // row within a round
  const int sch = ((tid * 16 >> 4) & (CH - 1)) ^ (srow & (CH - 1));
  constexpr int RPR = 8192 / (BK * 2);             // rows per round
  const ushort_t* pA[AR];
  const ushort_t* pB[BR];
  #pragma unroll
  for (int r = 0; r < AR; ++r) pA[r] = Ab + (size_t)(r * RPR + srow) * K + sch * 8;
  #pragma unroll
  for (int r = 0; r < BR; ++r) pB[r] = Bb + (size_t)(r * RPR + srow) * K + sch * 8;
  const int dL = tid * 8;                          // LDS dest elems (+ r*4096)

  // frag ds_read elem offsets at ks=0 (XOR ks*32 elems for ks=1)
  int oA[MF], oB[4];
  #pragma unroll
  for (int m = 0; m < MF; ++m) {
    const int r = wm * (BM / 2) + m * 16 + lrow;
    oA[m] = r * BK + (lk ^ (r & (CH - 1))) * 8;
  }
  #pragma unroll
  for (int n = 0; n < 4; ++n) {
    const int r = wn * 64 + n * 16 + lrow;
    oB[n] = r * BK + (lk ^ (r & (CH - 1))) * 8;
  }

  f32x4 acc[MF][4];
  #pragma unroll
  for (int m = 0; m < MF; ++m)
    #pragma unroll
    for (int n = 0; n < 4; ++n)
      acc[m][n] = (f32x4){0.f, 0.f, 0.f, 0.f};

  auto stage = [&](int s, int adv) {
    #pragma unroll
    for (int r = 0; r < AR; ++r) gload16(pA[r] + adv, (void*)&As[s][r * 4096 + dL]);
    #pragma unroll
    for (int r = 0; r < BR; ++r) gload16(pB[r] + adv, (void*)&Bs[s][r * 4096 + dL]);
  };

  // prologue: tiles 0,1 -> slots 0,1; retire tile0, keep tile1 in flight
  stage(0, 0);
  stage(1, BK);
  if constexpr (LPT == 4) VMW(4); else VMW(6);
  SB0(); BAR(); SB0();

  bf16x8 av[2][MF][KS], bv01[2][KS], bv23[2][KS];
  // pre-read tile0's P1 fragments (one-time exposed drain)
  #pragma unroll
  for (int m = 0; m < MF; ++m)
    #pragma unroll
    for (int ks = 0; ks < KS; ++ks)
      av[0][m][ks] = *(const bf16x8*)&As[0][oA[m] ^ (ks * 32)];
  #pragma unroll
  for (int n = 0; n < 2; ++n)
    #pragma unroll
    for (int ks = 0; ks < KS; ++ks)
      bv01[n][ks] = *(const bf16x8*)&Bs[0][oB[n] ^ (ks * 32)];

  #pragma unroll
  for (int t = 0; t < nt; ++t) {
    const int s = t % 3, s1 = (t + 1) % 3, s2 = (t + 2) % 3;
    const int p = t & 1;
    // ---- P1: stage t+2; read own bv23; MFMA H0 (n0-1) ----
    if (t + 2 < nt) stage(s2, (t + 2) * BK);
    #pragma unroll
    for (int n = 0; n < 2; ++n)
      #pragma unroll
      for (int ks = 0; ks < KS; ++ks)
        bv23[n][ks] = *(const bf16x8*)&Bs[s][oB[n + 2] ^ (ks * 32)];
    #pragma unroll
    for (int ks = 0; ks < KS; ++ks)
      #pragma unroll
      for (int m = 0; m < MF; ++m)
        #pragma unroll
        for (int n = 0; n < 2; ++n)
          acc[m][n] = __builtin_amdgcn_mfma_f32_16x16x32_bf16(av[p][m][ks], bv01[n][ks], acc[m][n], 0, 0, 0);
    SB0();
    if (t + 2 < nt) { if constexpr (LPT == 4) VMW(4); else VMW(6); }
    else            { VMW(0); }
    BAR(); SB0();
    // ---- P2: read t+1's av + bv01 from slot s1; MFMA H1 (n2-3) ----
    if (t + 1 < nt) {
      #pragma unroll
      for (int m = 0; m < MF; ++m)
        #pragma unroll
        for (int ks = 0; ks < KS; ++ks)
          av[p ^ 1][m][ks] = *(const bf16x8*)&As[s1][oA[m] ^ (ks * 32)];
      #pragma unroll
      for (int n = 0; n < 2; ++n)
        #pragma unroll
        for (int ks = 0; ks < KS; ++ks)
          bv01[n][ks] = *(const bf16x8*)&Bs[s1][oB[n] ^ (ks * 32)];
    }
    #pragma unroll
    for (int ks = 0; ks < KS; ++ks)
      #pragma unroll
      for (int m = 0; m < MF; ++m)
        #pragma unroll
        for (int n = 0; n < 2; ++n)
          acc[m][n + 2] = __builtin_amdgcn_mfma_f32_16x16x32_bf16(av[p][m][ks], bv23[n][ks], acc[m][n + 2], 0, 0, 0);
    SB0(); BAR(); SB0();
  }

  // epilogue: C/D layout col=lane&15, row=(lane>>4)*4+j
  #pragma unroll
  for (int m = 0; m < MF; ++m) {
    const int row0 = by * BM + wm * (BM / 2) + m * 16 + lk * 4;
    #pragma unroll
    for (int n = 0; n < 4; ++n) {
      const int col = bx * 256 + wn * 64 + n * 16 + lrow;
      #pragma unroll
      for (int j = 0; j < 4; ++j) {
        const size_t idx = (size_t)(row0 + j) * N + col;
        if constexpr (OUT_BF16) ((ushort_t*)Cp)[idx] = f2bf(acc[m][n][j]);
        else                    ((float*)Cp)[idx] = acc[m][n][j];
      }
    }
  }
}

// ---------------- middle: h_all, router softmax, M = sum_p w (x) h ----------------
__global__ __launch_bounds__(256) void middle_kernel(const unsigned short* __restrict__ AH,
                                                     const float* __restrict__ fp,
                                                     const float* __restrict__ femb,
                                                     const float* __restrict__ Wr,
                                                     unsigned short* __restrict__ Mout,
                                                     float* __restrict__ auxout) {
  __shared__ float G[16][16];
  __shared__ float hs[4][2][128];
  __shared__ float wsm[4][2][16];
  const int tid = threadIdx.x;
  {
    const int n = tid >> 4, j = tid & 15;
    float s = 0.f;
    #pragma unroll
    for (int ds = 0; ds < 64; ++ds) s += femb[n * 64 + ds] * Wr[ds * 16 + j];
    G[n][j] = s;
  }
  const int wv = tid >> 6, l = tid & 63;
  const int t = blockIdx.x * 4 + wv;

  float p0[16], p1[16];
  #pragma unroll
  for (int n = 0; n < 16; ++n) {
    p0[n] = fp[t * 16 + n];
    p1[n] = fp[T_TOK * 16 + t * 16 + n];
  }

  float h00 = 0.f, h01 = 0.f, h10 = 0.f, h11 = 0.f;
  const unsigned short* ahrow = AH + (size_t)t * NRCOL;
  #pragma unroll
  for (int n = 0; n < 16; ++n) {
    const unsigned int v = *(const unsigned int*)(ahrow + n * 128 + 2 * l);
    const float a0 = bfbits2f(v & 0xffffu);
    const float a1 = bfbits2f(v >> 16);
    h00 += a0 * p0[n]; h01 += a1 * p0[n];
    h10 += a0 * p1[n]; h11 += a1 * p1[n];
  }
  hs[wv][0][2 * l] = h00; hs[wv][0][2 * l + 1] = h01;
  hs[wv][1][2 * l] = h10; hs[wv][1][2 * l + 1] = h11;
  __syncthreads();

  if (l < 32) {
    const int p = l >> 4, j = l & 15;
    float s = 0.f;
    #pragma unroll
    for (int n = 0; n < 16; ++n) s += (p ? p1[n] : p0[n]) * G[n][j];
    const float* hp = hs[wv][p];
    const float* wr = Wr + 64 * 16 + j;
    float s0 = 0.f, s1 = 0.f, s2 = 0.f, s3 = 0.f;
    #pragma unroll
    for (int r = 0; r < 128; r += 4) {
      s0 += hp[r]     * wr[(r)     * 16];
      s1 += hp[r + 1] * wr[(r + 1) * 16];
      s2 += hp[r + 2] * wr[(r + 2) * 16];
      s3 += hp[r + 3] * wr[(r + 3) * 16];
    }
    s += (s0 + s1) + (s2 + s3);
    float mx = s;
    #pragma unroll
    for (int d = 1; d < 16; d <<= 1) mx = fmaxf(mx, __shfl_xor(mx, d, 64));
    const float e = __expf(s - mx);
    float sum = e;
    #pragma unroll
    for (int d = 1; d < 16; d <<= 1) sum += __shfl_xor(sum, d, 64);
    wsm[wv][p][j] = e / sum;
  }
  __syncthreads();

  unsigned short* mrow = Mout + (size_t)t * NRCOL;
  #pragma unroll
  for (int n = 0; n < 16; ++n) {
    const float w0 = wsm[wv][0][n], w1 = wsm[wv][1][n];
    const float m0 = w0 * h00 + w1 * h10;
    const float m1 = w0 * h01 + w1 * h11;
    const unsigned int pk = (unsigned)f2bf(m0) | ((unsigned)f2bf(m1) << 16);
    *(unsigned int*)(mrow + n * 128 + 2 * l) = pk;
  }
  if (blockIdx.x == 0 && tid == 0) auxout[0] = 0.f;
}

extern "C" void kernel_launch(void* const* d_in, const int* in_sizes, int n_in,
                              void* d_out, int out_size, void* d_ws, size_t ws_size,
                              hipStream_t stream) {
  const float* x    = (const float*)d_in[0];
  const float* fp   = (const float*)d_in[1];
  const float* fk   = (const float*)d_in[2];
  const float* rk   = (const float*)d_in[3];
  const float* femb = (const float*)d_in[4];
  const float* Wr   = (const float*)d_in[5];
  float* out = (float*)d_out;

  char* ws = (char*)d_ws;
  unsigned short* Xbf = (unsigned short*)ws;
  unsigned short* W1t = (unsigned short*)(ws + 16u * 1024 * 1024);
  unsigned short* Mb  = (unsigned short*)ws;
  unsigned short* W2t = (unsigned short*)(ws + 32u * 1024 * 1024);
  unsigned short* AH  = (unsigned short*)(ws + 36u * 1024 * 1024);

  cvt_f32_bf16<<<2048, 256, 0, stream>>>(x, Xbf, (T_TOK * DIM) / 4);
  tcvt<<<dim3(128 / 32, 1024 / 32, 16), 256, 0, stream>>>(fk, W1t, 1024, 128,
                                                          1024L * 128, 128L * 1024);
  tcvt<<<dim3(1024 / 32, 2048 / 32, 1), 256, 0, stream>>>(rk, W2t, 2048, 1024, 0, 0);
  // all_h = Xbf @ W1t^T -> AH bf16 [8192][2048]  (256x256 tile, BK=32)
  gemmP<256, 32, 1024, true><<<dim3(NRCOL / 256, T_TOK / 256), 512, 0, stream>>>(Xbf, W1t, AH, NRCOL);
  middle_kernel<<<T_TOK / 4, 256, 0, stream>>>(AH, fp, femb, Wr, Mb, out + 8388608);
  // output = Mb @ W2t^T -> f32 d_out [8192][1024]  (128x256 tile, BK=64)
  gemmP<128, 64, 2048, false><<<dim3(DIM / 256, T_TOK / 128), 512, 0, stream>>>(Mb, W2t, out, DIM);
}